// Round 2
// baseline (1343.960 us; speedup 1.0000x reference)
//
#include <hip/hip_runtime.h>

#define IMG   512
#define TILE  128
#define BUF   160      // logical buffer rows & cols (tile + 2*16)
#define OFF   16       // buffer (0,0) <-> global (tile_origin - 16)
#define NPATCH 1014    // 39 col-patches x 26 row-bands
#define LW    180      // physical row stride in words: 160 data + 5 gaps x 4 words
// Skewed LDS addressing: insert a 4-word gap after every 32 data words.
// Keeps float4 blocks contiguous & 16B-aligned; kills the mod-32 bank periodicity.
#define LIDX(y,x) ((y)*LW + (x) + ((((x)>>5))<<2))

__device__ __forceinline__ float mapf(float g) {
    float t = 3.9f * g;
    return t - t * g;          // R*g*(1-g), fma-contracted
}

// Computes g = conv(K') . M + 0.15*drive for a 4-wide x 6-tall patch.
// Rows y0..y0+5, output cols xr+2..xr+5 (reads cols xr..xr+7, b128-aligned).
__device__ __forceinline__ void conv_rows(
    const float* __restrict__ lds, int y0, int xr,
    const float* kk, const float* dv, float* g)
{
    const int xl = xr   + ((xr>>5)<<2);       // skewed offset, low float4
    const int xh = xr+4 + (((xr+4)>>5)<<2);   // skewed offset, high float4
    const float* p = lds + (y0 - 1) * LW;
    float4 aL = *(const float4*)(p + xl);
    float4 aH = *(const float4*)(p + xh);
    p += LW;
    float4 bL = *(const float4*)(p + xl);
    float4 bH = *(const float4*)(p + xh);
#pragma unroll
    for (int rr = 0; rr < 6; rr++) {
        p += LW;
        float4 cL = *(const float4*)(p + xl);
        float4 cH = *(const float4*)(p + xh);
        const float a[8] = {aL.x,aL.y,aL.z,aL.w,aH.x,aH.y,aH.z,aH.w};
        const float b[8] = {bL.x,bL.y,bL.z,bL.w,bH.x,bH.y,bH.z,bH.w};
        const float c[8] = {cL.x,cL.y,cL.z,cL.w,cH.x,cH.y,cH.z,cH.w};
#pragma unroll
        for (int k = 0; k < 4; k++) {
            float s;
            s  = kk[0]*a[k+1] + kk[1]*a[k+2] + kk[2]*a[k+3];
            s += kk[3]*b[k+1] + kk[4]*b[k+2] + kk[5]*b[k+3];
            s += kk[6]*c[k+1] + kk[7]*c[k+2] + kk[8]*c[k+3];
            g[rr*4+k] = s + 0.15f*dv[rr*4+k];
        }
        aL = bL; aH = bH; bL = cL; bH = cH;
    }
}

__global__ __launch_bounds__(1024) void cml_fused(
    const float* __restrict__ drive,
    const float* __restrict__ Kw,
    float* __restrict__ out)
{
    __shared__ float lds[BUF * LW];   // 112.5 KiB, 1 block/CU

    const int tid = threadIdx.x;
    const int bid = blockIdx.x;
    const int bc  = bid >> 4;               // image index (b*4+c), 0..255
    const int tl  = bid & 15;               // 4x4 tiles of 128x128
    const int ty0 = (tl >> 2) * TILE;
    const int tx0 = (tl & 3)  * TILE;
    const int gy0 = ty0 - OFF;              // buffer row r <-> global gy0+r
    const int gx0 = tx0 - OFF;
    const float* __restrict__ img  = drive + (size_t)bc * (IMG * IMG);
    float* __restrict__ oimg       = out   + (size_t)bc * (IMG * IMG);

    // Folded 3x3 kernel: K' = (0.85*0.3)*K + (0.85*0.7)*delta_center
    float kk[9];
    {
        const float c2 = 0.85f * 0.3f;
        const float* kp = Kw + (bc & 3) * 9;
#pragma unroll
        for (int q = 0; q < 9; q++) kk[q] = c2 * kp[q];
        kk[4] += 0.85f * 0.7f;
    }

    const bool active = tid < NPATCH;
    const int pi = tid / 39;                // row band 0..25
    const int pj = tid - pi * 39;           // col patch 0..38
    const int y0 = 2 + 6 * pi;              // output rows y0..y0+5
    const int xr = 4 * pj;                  // read base col (outputs xr+2..xr+5)

    // Drive values + in-image flags per patch cell, in registers (exact fp32)
    float dv[24], fc[24];
#pragma unroll
    for (int rr = 0; rr < 6; rr++) {
        const int gy = gy0 + y0 + rr;
#pragma unroll
        for (int k = 0; k < 4; k++) {
            const int gx = gx0 + xr + 2 + k;
            const bool in = ((unsigned)gy < IMG) && ((unsigned)gx < IMG);
            dv[rr*4+k] = in ? img[gy * IMG + gx] : 0.0f;
            fc[rr*4+k] = in ? 1.0f : 0.0f;
        }
    }

    // Init: M1 = map(drive) over full 160x160 buffer (out-of-image -> 0 -> map 0)
    for (int u = tid; u < BUF * 40; u += 1024) {
        const int yy = u / 40;
        const int xx = (u - yy * 40) * 4;
        const int gy  = gy0 + yy;
        const int gxb = gx0 + xx;                 // multiple of 4 -> aligned float4
        float4 v = make_float4(0.f, 0.f, 0.f, 0.f);
        if ((unsigned)gy < IMG && (unsigned)gxb < IMG)
            v = *(const float4*)(img + gy * IMG + gxb);
        v.x = mapf(v.x); v.y = mapf(v.y); v.z = mapf(v.z); v.w = mapf(v.w);
        *(float4*)(lds + LIDX(yy, xx)) = v;
    }
    __syncthreads();

    const int xl2 = xr+2 + ((xr>>5)<<2);        // skewed write offsets
    const int xh2 = xr+4 + (((xr+4)>>5)<<2);

    float st[24];
#pragma unroll 1
    for (int step = 0; step < 14; step++) {
        if (active) {
            conv_rows(lds, y0, xr, kk, dv, st);   // st = grid values
            // map + zero-pad flags -> st = M_{t+1}
#pragma unroll
            for (int i = 0; i < 24; i++) {
                const float g = st[i];
                const float t = 3.9f * g;
                st[i] = (t - t * g) * fc[i];
            }
        }
        __syncthreads();   // all reads done before any write
        if (active) {
            float* w = (float*)lds + y0 * LW;
#pragma unroll
            for (int rr = 0; rr < 6; rr++) {
                *(float2*)(w + xl2) = make_float2(st[rr*4+0], st[rr*4+1]);
                *(float2*)(w + xh2) = make_float2(st[rr*4+2], st[rr*4+3]);
                w += LW;
            }
        }
        __syncthreads();   // writes done before next step's reads
    }

    // Step 15: compute grid, clip, store tile directly to global
    if (active) {
        conv_rows(lds, y0, xr, kk, dv, st);
#pragma unroll
        for (int rr = 0; rr < 6; rr++) {
            const int r = y0 + rr;
            if (r >= OFF && r < OFF + TILE) {
#pragma unroll
                for (int k = 0; k < 4; k++) {
                    const int x = xr + 2 + k;
                    if (x >= OFF && x < OFF + TILE) {
                        float g = st[rr*4+k];
                        g = fminf(fmaxf(g, 1e-4f), 1.0f - 1e-4f);
                        oimg[(gy0 + r) * IMG + (gx0 + x)] = g;
                    }
                }
            }
        }
    }
}

extern "C" void kernel_launch(void* const* d_in, const int* in_sizes, int n_in,
                              void* d_out, int out_size, void* d_ws, size_t ws_size,
                              hipStream_t stream)
{
    const float* drive = (const float*)d_in[0];
    const float* Kw    = (const float*)d_in[1];
    float* out         = (float*)d_out;
    // 256 images x 16 tiles = 4096 blocks, 1024 threads (16 waves, 1 block/CU by LDS)
    cml_fused<<<dim3(4096), dim3(1024), 0, stream>>>(drive, Kw, out);
}

// Round 3
// 1259.491 us; speedup vs baseline: 1.0671x; 1.0671x over previous
//
#include <hip/hip_runtime.h>

#define IMG   512
#define TILE  128
#define OFF_Y 16          // row halo
#define OFF_X 18          // col halo (left); buffer col 18 == tile col 0
#define BUFY  160
#define BUFX  164         // data cols (tile 128 + 18 + 18)
#define LW    172         // row stride in words; mult of 4; 6*LW*4 % 128 == 32
#define NP    1014        // 39 col-patches x 26 row-bands

__device__ __forceinline__ float mapf(float g) {
    float t = 3.9f * g;
    return t - t * g;          // R*g*(1-g)
}

__global__ __launch_bounds__(1024, 4) void cml_fused(
    const float* __restrict__ drive,
    const float* __restrict__ Kw,
    float* __restrict__ out)
{
    __shared__ float lds[BUFY * LW];   // 107.5 KiB, 1 block/CU

    const int tid = threadIdx.x;
    const int bid = blockIdx.x;
    const int bc  = bid >> 4;               // image index (b*4+c)
    const int tl  = bid & 15;               // 4x4 tiles of 128x128
    const int gy0 = (tl >> 2) * TILE - OFF_Y;   // buffer row r <-> global gy0+r
    const int gx0 = (tl & 3)  * TILE - OFF_X;   // buffer col x <-> global gx0+x
    const float* __restrict__ img  = drive + (size_t)bc * (IMG*IMG);
    float*       __restrict__ oimg = out   + (size_t)bc * (IMG*IMG);

    // Folded 3x3 kernel: K' = (0.85*0.3)*K + (0.85*0.7)*delta_center
    float kk[9];
    {
        const float c2 = 0.85f * 0.3f;
        const float* kp = Kw + (bc & 3) * 9;
#pragma unroll
        for (int q = 0; q < 9; q++) kk[q] = c2 * kp[q];
        kk[4] += 0.85f * 0.7f;
    }

    // Patch assignment; inactive tail lanes duplicate the last patch (benign:
    // identical values to identical addresses).
    const int t2 = tid < NP ? tid : NP - 1;
    const int pi = t2 / 39;                 // row band 0..25
    const int pj = t2 - pi * 39;            // col patch 0..38
    const int y0 = 2 + 6 * pi;              // output rows y0..y0+5
    const int xw = 4 * pj;                  // read window cols [xw, xw+12)
                                            // owned cols [xw+4, xw+8)  (16B-aligned)

    // Drive (pre-scaled by BETA) + boundary flags, in registers
    float dvs[24], fx[4], fy[6];
#pragma unroll
    for (int k = 0; k < 4; k++)
        fx[k] = ((unsigned)(gx0 + xw + 4 + k) < IMG) ? 1.0f : 0.0f;
#pragma unroll
    for (int rr = 0; rr < 6; rr++) {
        const int gy = gy0 + y0 + rr;
        fy[rr] = ((unsigned)gy < IMG) ? 1.0f : 0.0f;
#pragma unroll
        for (int k = 0; k < 4; k++) {
            const int gx = gx0 + xw + 4 + k;
            dvs[rr*4+k] = (((unsigned)gy < IMG) && ((unsigned)gx < IMG))
                        ? 0.15f * img[gy*IMG + gx] : 0.0f;
        }
    }

    // Init: M1 = map(drive) over the full buffer. float2 granularity because
    // gx0 == 2 (mod 4): float4 would be misaligned and cross image rows.
    for (int u = tid; u < BUFY * (LW/2); u += 1024) {
        const int yy = u / (LW/2);
        const int xx = (u - yy * (LW/2)) * 2;
        const int gy = gy0 + yy;
        const int gxb = gx0 + xx;               // even -> aligned float2
        float2 v = make_float2(0.f, 0.f);
        if (xx < BUFX && (unsigned)gy < IMG && (unsigned)gxb < IMG)
            v = *(const float2*)(img + gy*IMG + gxb);   // gxb<=510: no row cross
        v.x = mapf(v.x); v.y = mapf(v.y);
        *(float2*)(lds + yy*LW + xx) = v;
    }
    __syncthreads();

    float st[24];
#pragma unroll 1
    for (int step = 0; step < 14; step++) {
        {
            // rolling 3-row window, 3 aligned b128 reads per row
            float a[12], b[12], c[12];
            const float* p = lds + (y0 - 1) * LW + xw;
            *(float4*)&a[0] = *(const float4*)(p);
            *(float4*)&a[4] = *(const float4*)(p + 4);
            *(float4*)&a[8] = *(const float4*)(p + 8);
            p += LW;
            *(float4*)&b[0] = *(const float4*)(p);
            *(float4*)&b[4] = *(const float4*)(p + 4);
            *(float4*)&b[8] = *(const float4*)(p + 8);
#pragma unroll
            for (int rr = 0; rr < 6; rr++) {
                p += LW;
                *(float4*)&c[0] = *(const float4*)(p);
                *(float4*)&c[4] = *(const float4*)(p + 4);
                *(float4*)&c[8] = *(const float4*)(p + 8);
                const float fyr = fy[rr];
#pragma unroll
                for (int k = 0; k < 4; k++) {
                    float s = dvs[rr*4+k];
                    s += kk[0]*a[3+k] + kk[1]*a[4+k] + kk[2]*a[5+k];
                    s += kk[3]*b[3+k] + kk[4]*b[4+k] + kk[5]*b[5+k];
                    s += kk[6]*c[3+k] + kk[7]*c[4+k] + kk[8]*c[5+k];
                    const float t = 3.9f * s;
                    st[rr*4+k] = (t - t*s) * fyr * fx[k];
                }
#pragma unroll
                for (int q = 0; q < 12; q++) { a[q] = b[q]; b[q] = c[q]; }
            }
        }
        __syncthreads();   // all reads done before any write
        {
            float* w = lds + y0 * LW + xw + 4;
#pragma unroll
            for (int rr = 0; rr < 6; rr++) {
                *(float4*)w = make_float4(st[rr*4+0], st[rr*4+1],
                                          st[rr*4+2], st[rr*4+3]);
                w += LW;
            }
        }
        __syncthreads();   // writes done before next step's reads
    }

    // Step 15: compute grid (no map), clip, store tile interior to global.
    {
        float a[12], b[12], c[12];
        const float* p = lds + (y0 - 1) * LW + xw;
        *(float4*)&a[0] = *(const float4*)(p);
        *(float4*)&a[4] = *(const float4*)(p + 4);
        *(float4*)&a[8] = *(const float4*)(p + 8);
        p += LW;
        *(float4*)&b[0] = *(const float4*)(p);
        *(float4*)&b[4] = *(const float4*)(p + 4);
        *(float4*)&b[8] = *(const float4*)(p + 8);
#pragma unroll
        for (int rr = 0; rr < 6; rr++) {
            p += LW;
            *(float4*)&c[0] = *(const float4*)(p);
            *(float4*)&c[4] = *(const float4*)(p + 4);
            *(float4*)&c[8] = *(const float4*)(p + 8);
#pragma unroll
            for (int k = 0; k < 4; k++) {
                float s = dvs[rr*4+k];
                s += kk[0]*a[3+k] + kk[1]*a[4+k] + kk[2]*a[5+k];
                s += kk[3]*b[3+k] + kk[4]*b[4+k] + kk[5]*b[5+k];
                s += kk[6]*c[3+k] + kk[7]*c[4+k] + kk[8]*c[5+k];
                st[rr*4+k] = fminf(fmaxf(s, 1e-4f), 1.0f - 1e-4f);
            }
#pragma unroll
            for (int q = 0; q < 12; q++) { a[q] = b[q]; b[q] = c[q]; }
        }
    }
    // Guarded float2 stores (pairs respect the [18,146) interior split; gx0+col even)
#pragma unroll
    for (int rr = 0; rr < 6; rr++) {
        const int r = y0 + rr;
        if (r >= OFF_Y && r < OFF_Y + TILE) {
#pragma unroll
            for (int h = 0; h < 2; h++) {
                const int col = xw + 4 + 2*h;
                if (col >= OFF_X && col + 1 < OFF_X + TILE) {
                    *(float2*)(oimg + (size_t)(gy0 + r) * IMG + (gx0 + col)) =
                        make_float2(st[rr*4 + 2*h], st[rr*4 + 2*h + 1]);
                }
            }
        }
    }
}

extern "C" void kernel_launch(void* const* d_in, const int* in_sizes, int n_in,
                              void* d_out, int out_size, void* d_ws, size_t ws_size,
                              hipStream_t stream)
{
    const float* drive = (const float*)d_in[0];
    const float* Kw    = (const float*)d_in[1];
    float* out         = (float*)d_out;
    // 256 images x 16 tiles = 4096 blocks, 1024 threads (16 waves, 1 block/CU)
    cml_fused<<<dim3(4096), dim3(1024), 0, stream>>>(drive, Kw, out);
}

// Round 4
// 1248.147 us; speedup vs baseline: 1.0768x; 1.0091x over previous
//
#include <hip/hip_runtime.h>

#define IMG   512
#define TILE  128
#define OFF_Y 16          // row halo
#define OFF_X 18          // col halo (left); buffer col 18 == tile col 0
#define BUFY  160
#define BUFX  164         // data cols (tile 128 + 18 + 18)
#define LW    172         // row stride in words (mult of 4 -> b128-aligned rows)
#define NP    1014        // 39 col-patches x 26 row-bands

__device__ __forceinline__ float mapf(float g) {
    float t = 3.9f * g;
    return t - t * g;          // R*g*(1-g)
}

// Read the 6-word stencil window [c-1, c+5) for owned cols c=xw+4:
// one aligned b128 (owned words) + two scalars (ds_read2_b32).
__device__ __forceinline__ void read_row(const float* __restrict__ p, int xw,
                                         float* m /*[6]*/) {
    const float4 mid = *(const float4*)(p + xw + 4);
    m[0] = p[xw + 3];
    m[1] = mid.x; m[2] = mid.y; m[3] = mid.z; m[4] = mid.w;
    m[5] = p[xw + 8];
}

__global__ __launch_bounds__(1024, 4) void cml_fused(
    const float* __restrict__ drive,
    const float* __restrict__ Kw,
    float* __restrict__ out)
{
    __shared__ float lds[BUFY * LW];   // 107.5 KiB, 1 block/CU

    const int tid = threadIdx.x;
    const int bid = blockIdx.x;
    const int bc  = bid >> 4;               // image index (b*4+c)
    const int tl  = bid & 15;               // 4x4 tiles of 128x128
    const int gy0 = (tl >> 2) * TILE - OFF_Y;   // buffer row r <-> global gy0+r
    const int gx0 = (tl & 3)  * TILE - OFF_X;   // buffer col x <-> global gx0+x
    const float* __restrict__ img  = drive + (size_t)bc * (IMG*IMG);
    float*       __restrict__ oimg = out   + (size_t)bc * (IMG*IMG);

    // Folded 3x3 kernel: K' = (0.85*0.3)*K + (0.85*0.7)*delta_center
    float kk[9];
    {
        const float c2 = 0.85f * 0.3f;
        const float* kp = Kw + (bc & 3) * 9;
#pragma unroll
        for (int q = 0; q < 9; q++) kk[q] = c2 * kp[q];
        kk[4] += 0.85f * 0.7f;
    }

    // Patch assignment; tail lanes duplicate the last patch (benign).
    const int t2 = tid < NP ? tid : NP - 1;
    const int pi = t2 / 39;                 // row band 0..25
    const int pj = t2 - pi * 39;            // col patch 0..38
    const int y0 = 2 + 6 * pi;              // output rows y0..y0+5
    const int xw = 4 * pj;                  // owned cols [xw+4, xw+8)

    // Drive (pre-scaled by BETA) + boundary flags, in registers
    float dvs[24], fx[4], fy[6];
#pragma unroll
    for (int k = 0; k < 4; k++)
        fx[k] = ((unsigned)(gx0 + xw + 4 + k) < IMG) ? 1.0f : 0.0f;
#pragma unroll
    for (int rr = 0; rr < 6; rr++) {
        const int gy = gy0 + y0 + rr;
        fy[rr] = ((unsigned)gy < IMG) ? 1.0f : 0.0f;
#pragma unroll
        for (int k = 0; k < 4; k++) {
            const int gx = gx0 + xw + 4 + k;
            dvs[rr*4+k] = (((unsigned)gy < IMG) && ((unsigned)gx < IMG))
                        ? 0.15f * img[gy*IMG + gx] : 0.0f;
        }
    }

    // Init: M1 = map(drive) over the full buffer (float2: gx0 == 2 mod 4).
    for (int u = tid; u < BUFY * (LW/2); u += 1024) {
        const int yy = u / (LW/2);
        const int xx = (u - yy * (LW/2)) * 2;
        const int gy = gy0 + yy;
        const int gxb = gx0 + xx;               // even -> aligned float2
        float2 v = make_float2(0.f, 0.f);
        if (xx < BUFX && (unsigned)gy < IMG && (unsigned)gxb < IMG)
            v = *(const float2*)(img + gy*IMG + gxb);   // gxb<=510: no row cross
        v.x = mapf(v.x); v.y = mapf(v.y);
        *(float2*)(lds + yy*LW + xx) = v;
    }
    __syncthreads();

    float st[24];
#pragma unroll 1
    for (int step = 0; step < 14; step++) {
        {
            // rolling 3-row window of 6-word stencil rows
            float a[6], b[6], c[6];
            const float* p = lds + (y0 - 1) * LW;
            read_row(p, xw, a);  p += LW;
            read_row(p, xw, b);
#pragma unroll
            for (int rr = 0; rr < 6; rr++) {
                p += LW;
                read_row(p, xw, c);
                const float fyr = fy[rr];
#pragma unroll
                for (int k = 0; k < 4; k++) {
                    float s = dvs[rr*4+k];
                    s += kk[0]*a[k] + kk[1]*a[k+1] + kk[2]*a[k+2];
                    s += kk[3]*b[k] + kk[4]*b[k+1] + kk[5]*b[k+2];
                    s += kk[6]*c[k] + kk[7]*c[k+1] + kk[8]*c[k+2];
                    const float t = 3.9f * s;
                    st[rr*4+k] = (t - t*s) * fyr * fx[k];
                }
#pragma unroll
                for (int q = 0; q < 6; q++) { a[q] = b[q]; b[q] = c[q]; }
            }
        }
        __syncthreads();   // all reads done before any write
        {
            float* w = lds + y0 * LW + xw + 4;
#pragma unroll
            for (int rr = 0; rr < 6; rr++) {
                *(float4*)w = make_float4(st[rr*4+0], st[rr*4+1],
                                          st[rr*4+2], st[rr*4+3]);
                w += LW;
            }
        }
        __syncthreads();   // writes done before next step's reads
    }

    // Step 15: compute grid (no map), clip, store tile interior to global.
    {
        float a[6], b[6], c[6];
        const float* p = lds + (y0 - 1) * LW;
        read_row(p, xw, a);  p += LW;
        read_row(p, xw, b);
#pragma unroll
        for (int rr = 0; rr < 6; rr++) {
            p += LW;
            read_row(p, xw, c);
#pragma unroll
            for (int k = 0; k < 4; k++) {
                float s = dvs[rr*4+k];
                s += kk[0]*a[k] + kk[1]*a[k+1] + kk[2]*a[k+2];
                s += kk[3]*b[k] + kk[4]*b[k+1] + kk[5]*b[k+2];
                s += kk[6]*c[k] + kk[7]*c[k+1] + kk[8]*c[k+2];
                st[rr*4+k] = fminf(fmaxf(s, 1e-4f), 1.0f - 1e-4f);
            }
#pragma unroll
            for (int q = 0; q < 6; q++) { a[q] = b[q]; b[q] = c[q]; }
        }
    }
    // Guarded float2 stores (pairs respect the [18,146) interior split)
#pragma unroll
    for (int rr = 0; rr < 6; rr++) {
        const int r = y0 + rr;
        if (r >= OFF_Y && r < OFF_Y + TILE) {
#pragma unroll
            for (int h = 0; h < 2; h++) {
                const int col = xw + 4 + 2*h;
                if (col >= OFF_X && col + 1 < OFF_X + TILE) {
                    *(float2*)(oimg + (size_t)(gy0 + r) * IMG + (gx0 + col)) =
                        make_float2(st[rr*4 + 2*h], st[rr*4 + 2*h + 1]);
                }
            }
        }
    }
}

extern "C" void kernel_launch(void* const* d_in, const int* in_sizes, int n_in,
                              void* d_out, int out_size, void* d_ws, size_t ws_size,
                              hipStream_t stream)
{
    const float* drive = (const float*)d_in[0];
    const float* Kw    = (const float*)d_in[1];
    float* out         = (float*)d_out;
    // 256 images x 16 tiles = 4096 blocks, 1024 threads (16 waves, 1 block/CU)
    cml_fused<<<dim3(4096), dim3(1024), 0, stream>>>(drive, Kw, out);
}